// Round 7
// baseline (179.185 us; speedup 1.0000x reference)
//
#include <hip/hip_runtime.h>
#include <stdint.h>

#define NR 5000
#define NRM1 4999
#define W 640
#define NBLK 2500          // block b handles triu rows b and 4998-b (exactly 5000 elems)
#define PCOUNT 12497500.0f
#define LOG2E 1.44269504088896340736f
#define LN2   0.69314718055994530942f

// Loss in log2 domain (ln2 applied once at the end):
//   g != 0 : log2(1 + 2^(-g*d*log2e))   [= softplus(-g*d)/ln2]
//   g == 0 : d * (d*log2e)              [= d^2/ln2]
__device__ __forceinline__ float loss2(float zr, float zj, float g) {
    const float d  = zr - zj;
    const float dl = d * LOG2E;
    const float lg = __log2f(1.0f + exp2f(-g * dl));
    return (g != 0.0f) ? lg : d * dl;
}

__global__ __launch_bounds__(256) void fused_loss(const float* __restrict__ x,
                                                  const int* __restrict__ centers,
                                                  const float* __restrict__ gt,
                                                  float* __restrict__ partials,
                                                  unsigned int* __restrict__ counter,
                                                  float* __restrict__ out) {
    __shared__ float sz[NR];
    __shared__ float wsum[4];
    __shared__ bool amLast;
    const int tid = threadIdx.x;
    const int b = blockIdx.x;

    // Per-block gather of the z-range this block needs: j in [b, NR).
    // centers is (NR,2) int32 -> int2; x (1.2MB) is L1/L2-resident.
    for (int j = b + tid; j < NR; j += 256) {
        const int2 rc = ((const int2*)centers)[j];
        sz[j] = x[rc.x * W + rc.y];
    }
    __syncthreads();

    float a0 = 0.0f, a1 = 0.0f, a2 = 0.0f, a3 = 0.0f;

    #pragma unroll 1
    for (int pass = 0; pass < 2; ++pass) {
        const int r = (pass == 0) ? b : (NR - 2 - b);
        if (pass == 1 && r <= b) break;
        const int off = r * NRM1 - (r * (r - 1)) / 2;   // triu row offset, fits i32
        const float zr = sz[r];
        const int len = NRM1 - r;                        // j runs r+1 .. NR-1
        const float* __restrict__ gtr = gt + off;
        const int zb = r + 1;

        int t = tid;
        for (; t + 768 < len; t += 1024) {               // 4 indep loads, 4 acc chains
            const float g0 = gtr[t];
            const float g1 = gtr[t + 256];
            const float g2 = gtr[t + 512];
            const float g3 = gtr[t + 768];
            a0 += loss2(zr, sz[zb + t],       g0);
            a1 += loss2(zr, sz[zb + t + 256], g1);
            a2 += loss2(zr, sz[zb + t + 512], g2);
            a3 += loss2(zr, sz[zb + t + 768], g3);
        }
        for (; t < len; t += 256)
            a0 += loss2(zr, sz[zb + t], gtr[t]);
    }

    float acc = (a0 + a1) + (a2 + a3);

    // deterministic block reduction: wave shuffle tree + LDS across 4 waves
    for (int o = 32; o > 0; o >>= 1) acc += __shfl_down(acc, o, 64);
    if ((tid & 63) == 0) wsum[tid >> 6] = acc;
    __syncthreads();

    if (tid == 0) {
        const float p = (wsum[0] + wsum[1]) + (wsum[2] + wsum[3]);
        __hip_atomic_store(&partials[b], p, __ATOMIC_RELEASE, __HIP_MEMORY_SCOPE_AGENT);
        const unsigned int old = __hip_atomic_fetch_add(counter, 1u, __ATOMIC_ACQ_REL,
                                                        __HIP_MEMORY_SCOPE_AGENT);
        // counter is memset to 0 by kernel_launch before this kernel, so
        // old == NBLK-1 identifies the TRUE last arrival: all other blocks
        // have release-stored their partial before incrementing.
        amLast = (old == NBLK - 1);
    }
    __syncthreads();

    if (amLast) {
        // fixed-order reduction -> bit-identical output regardless of which
        // block executes it (determinism requirement).
        float facc = 0.0f;
        for (int i = tid; i < NBLK; i += 256)
            facc += __hip_atomic_load(&partials[i], __ATOMIC_ACQUIRE,
                                      __HIP_MEMORY_SCOPE_AGENT);
        for (int o = 32; o > 0; o >>= 1) facc += __shfl_down(facc, o, 64);
        if ((tid & 63) == 0) wsum[tid >> 6] = facc;
        __syncthreads();
        if (tid == 0)
            out[0] = ((wsum[0] + wsum[1]) + (wsum[2] + wsum[3])) * (LN2 / PCOUNT);
    }
}

extern "C" void kernel_launch(void* const* d_in, const int* in_sizes, int n_in,
                              void* d_out, int out_size, void* d_ws, size_t ws_size,
                              hipStream_t stream) {
    const float* x       = (const float*)d_in[0];   // (480,640) f32
    const float* gt      = (const float*)d_in[1];   // (P,) f32
    const int*   centers = (const int*)d_in[2];     // (5000,2) int32
    float* out = (float*)d_out;                     // scalar f32

    unsigned int* counter = (unsigned int*)d_ws;    // 1 uint, zeroed per call
    float* partials       = (float*)d_ws + 64;      // NBLK floats (own cachelines)

    hipMemsetAsync(counter, 0, sizeof(unsigned int), stream);  // graph memset node
    fused_loss<<<NBLK, 256, 0, stream>>>(x, centers, gt, partials, counter, out);
}

// Round 8
// 117.137 us; speedup vs baseline: 1.5297x; 1.5297x over previous
//
#include <hip/hip_runtime.h>
#include <stdint.h>

#define NR 5000
#define NRM1 4999
#define W 640
#define NBLK 2500          // block b handles triu rows b and 4998-b (exactly 5000 elems)
#define PCOUNT 12497500.0f
#define LOG2E 1.44269504088896340736f
#define LN2   0.69314718055994530942f

// ---------------- Kernel 1: gather z = x[rows, cols] (once, coalesced-index) ----
__global__ void gather_z(const float* __restrict__ x,
                         const int* __restrict__ centers,
                         float* __restrict__ z) {
    int t = blockIdx.x * blockDim.x + threadIdx.x;
    if (t < NR) {
        const int2 rc = ((const int2*)centers)[t];
        z[t] = x[rc.x * W + rc.y];
    }
}

// Loss in log2 domain (ln2 applied once at the end):
//   g != 0 : log2(1 + 2^(-g*d*log2e))   [= softplus(-g*d)/ln2]
//   g == 0 : d * (d*log2e)              [= d^2/ln2]
__device__ __forceinline__ float loss2(float zr, float zj, float g) {
    const float d  = zr - zj;
    const float dl = d * LOG2E;
    const float lg = __log2f(1.0f + exp2f(-g * dl));
    return (g != 0.0f) ? lg : d * dl;
}

// Sum over one triu row (len elems) across 256 threads; float4 body on gt
// (peeled to 16B alignment), scalar z reads (z is 20KB, L1/L2-resident).
__device__ __forceinline__ float row_sum(const float* __restrict__ gtr,
                                         const float* __restrict__ zrow,
                                         float zr, int len, int tid) {
    int head = (int)((0u - (uint32_t)(((uintptr_t)gtr) >> 2)) & 3u);
    if (head > len) head = len;
    float a0 = 0.0f, a1 = 0.0f, a2 = 0.0f, a3 = 0.0f;
    if (tid < head) a0 += loss2(zr, zrow[tid], gtr[tid]);

    const int nv = (len - head) >> 2;
    const float4* __restrict__ gv = (const float4*)(gtr + head);
    const float* __restrict__ zb = zrow + head;
    for (int v = tid; v < nv; v += 256) {
        const float4 g = gv[v];
        const int base = 4 * v;
        a0 += loss2(zr, zb[base + 0], g.x);
        a1 += loss2(zr, zb[base + 1], g.y);
        a2 += loss2(zr, zb[base + 2], g.z);
        a3 += loss2(zr, zb[base + 3], g.w);
    }

    const int ti = head + 4 * nv + tid;
    if (ti < len) a1 += loss2(zr, zrow[ti], gtr[ti]);
    return (a0 + a1) + (a2 + a3);
}

// ---------------- Kernel 2: pair loss + fused last-block final reduce ----------
__global__ __launch_bounds__(256) void pair_loss(const float* __restrict__ gt,
                                                 const float* __restrict__ z,
                                                 float* __restrict__ partials,
                                                 unsigned int* __restrict__ counter,
                                                 float* __restrict__ out) {
    __shared__ float wsum[4];
    __shared__ bool amLast;
    const int tid = threadIdx.x;
    const int b = blockIdx.x;
    float acc = 0.0f;

    {   // row r1 = b, len 4999-b
        const int r = b;
        const int off = r * NRM1 - (r * (r - 1)) / 2;   // fits i32
        acc += row_sum(gt + off, z + r + 1, z[r], NRM1 - r, tid);
    }
    const int r2 = NR - 2 - b;
    if (r2 > b) {  // row r2, len b+1
        const int off = r2 * NRM1 - (r2 * (r2 - 1)) / 2;
        acc += row_sum(gt + off, z + r2 + 1, z[r2], NRM1 - r2, tid);
    }

    // deterministic block reduction: wave shuffle tree + LDS across 4 waves
    for (int o = 32; o > 0; o >>= 1) acc += __shfl_down(acc, o, 64);
    if ((tid & 63) == 0) wsum[tid >> 6] = acc;
    __syncthreads();

    if (tid == 0) {
        const float p = (wsum[0] + wsum[1]) + (wsum[2] + wsum[3]);
        __hip_atomic_store(&partials[b], p, __ATOMIC_RELEASE, __HIP_MEMORY_SCOPE_AGENT);
        const unsigned int old = __hip_atomic_fetch_add(counter, 1u, __ATOMIC_ACQ_REL,
                                                        __HIP_MEMORY_SCOPE_AGENT);
        // counter memset to 0 each call -> old == NBLK-1 is the TRUE last arrival.
        amLast = (old == NBLK - 1);
    }
    __syncthreads();

    if (amLast) {
        // fixed-order reduction -> bit-identical result whichever block is last.
        float facc = 0.0f;
        for (int i = tid; i < NBLK; i += 256)
            facc += __hip_atomic_load(&partials[i], __ATOMIC_ACQUIRE,
                                      __HIP_MEMORY_SCOPE_AGENT);
        for (int o = 32; o > 0; o >>= 1) facc += __shfl_down(facc, o, 64);
        if ((tid & 63) == 0) wsum[tid >> 6] = facc;
        __syncthreads();
        if (tid == 0)
            out[0] = ((wsum[0] + wsum[1]) + (wsum[2] + wsum[3])) * (LN2 / PCOUNT);
    }
}

extern "C" void kernel_launch(void* const* d_in, const int* in_sizes, int n_in,
                              void* d_out, int out_size, void* d_ws, size_t ws_size,
                              hipStream_t stream) {
    const float* x       = (const float*)d_in[0];   // (480,640) f32
    const float* gt      = (const float*)d_in[1];   // (P,) f32
    const int*   centers = (const int*)d_in[2];     // (5000,2) int32
    float* out = (float*)d_out;                     // scalar f32

    unsigned int* counter = (unsigned int*)d_ws;    // 1 uint, zeroed per call
    float* z              = (float*)d_ws + 64;      // NR floats
    float* partials       = (float*)d_ws + 64 + NR; // NBLK floats

    hipMemsetAsync(counter, 0, sizeof(unsigned int), stream);  // graph memset node
    gather_z<<<(NR + 255) / 256, 256, 0, stream>>>(x, centers, z);
    pair_loss<<<NBLK, 256, 0, stream>>>(gt, z, partials, counter, out);
}

// Round 9
// 28.198 us; speedup vs baseline: 6.3545x; 4.1541x over previous
//
#include <hip/hip_runtime.h>
#include <stdint.h>

#define NR 5000
#define NRM1 4999
#define W 640
#define NBLK 2500          // block b handles triu rows b and 4998-b (exactly 5000 elems)
#define PCOUNT 12497500.0f
#define LOG2E 1.44269504088896340736f
#define LN2   0.69314718055994530942f

// ---------------- Kernel 1: gather z = x[rows, cols] (once) ----------------
__global__ void gather_z(const float* __restrict__ x,
                         const int* __restrict__ centers,
                         float* __restrict__ z) {
    int t = blockIdx.x * blockDim.x + threadIdx.x;
    if (t < NR) {
        const int2 rc = ((const int2*)centers)[t];
        z[t] = x[rc.x * W + rc.y];
    }
}

// Loss in log2 domain (ln2 applied once in final_reduce):
//   g != 0 : log2(1 + 2^(-g*d*log2e))   [= softplus(-g*d)/ln2]
//   g == 0 : d * (d*log2e)              [= d^2/ln2]
__device__ __forceinline__ float loss2(float zr, float zj, float g) {
    const float d  = zr - zj;
    const float dl = d * LOG2E;
    const float lg = __log2f(1.0f + exp2f(-g * dl));
    return (g != 0.0f) ? lg : d * dl;
}

// Sum over one triu row (len elems) across 256 threads.
// gt: float4 body (peeled to 16B alignment) — the ONLY VMEM stream here.
// z: from LDS (sz), DS pipe, stride-1 within a float4 group.
__device__ __forceinline__ float row_sum(const float* __restrict__ gtr,
                                         const float* __restrict__ szrow,
                                         float zr, int len, int tid) {
    int head = (int)((0u - (uint32_t)(((uintptr_t)gtr) >> 2)) & 3u);
    if (head > len) head = len;
    float a0 = 0.0f, a1 = 0.0f, a2 = 0.0f, a3 = 0.0f;
    if (tid < head) a0 += loss2(zr, szrow[tid], gtr[tid]);

    const int nv = (len - head) >> 2;
    const float4* __restrict__ gv = (const float4*)(gtr + head);
    const float* __restrict__ zb = szrow + head;
    for (int v = tid; v < nv; v += 256) {
        const float4 g = gv[v];
        const int base = 4 * v;
        a0 += loss2(zr, zb[base + 0], g.x);
        a1 += loss2(zr, zb[base + 1], g.y);
        a2 += loss2(zr, zb[base + 2], g.z);
        a3 += loss2(zr, zb[base + 3], g.w);
    }

    const int ti = head + 4 * nv + tid;
    if (ti < len) a1 += loss2(zr, szrow[ti], gtr[ti]);
    return (a0 + a1) + (a2 + a3);
}

// ---------------- Kernel 2: per-pair loss, per-block partial sums ----------------
__global__ __launch_bounds__(256) void pair_loss(const float* __restrict__ gt,
                                                 const float* __restrict__ z,
                                                 float* __restrict__ partials) {
    __shared__ float sz[NR];        // 20000 B -> 8 blocks/CU, 32 waves/CU
    __shared__ float wsum[4];
    const int tid = threadIdx.x;
    const int b = blockIdx.x;

    // Stage z -> LDS with float4 loads (z is 256B-aligned) + b128 writes.
    // 1250 float4s over 256 threads ~= 5 per thread; one barrier.
    const float4* __restrict__ zf4 = (const float4*)z;
    for (int t = tid; t < NR / 4; t += 256) {
        const float4 v = zf4[t];
        *(float4*)&sz[4 * t] = v;
    }
    __syncthreads();

    float acc = 0.0f;
    {   // row r1 = b, len 4999-b
        const int r = b;
        const int off = r * NRM1 - (r * (r - 1)) / 2;   // fits i32
        acc += row_sum(gt + off, sz + r + 1, sz[r], NRM1 - r, tid);
    }
    const int r2 = NR - 2 - b;
    if (r2 > b) {  // row r2, len b+1
        const int off = r2 * NRM1 - (r2 * (r2 - 1)) / 2;
        acc += row_sum(gt + off, sz + r2 + 1, sz[r2], NRM1 - r2, tid);
    }

    // deterministic block reduction: wave shuffle tree + LDS across 4 waves
    for (int o = 32; o > 0; o >>= 1) acc += __shfl_down(acc, o, 64);
    if ((tid & 63) == 0) wsum[tid >> 6] = acc;
    __syncthreads();
    if (tid == 0)
        partials[b] = (wsum[0] + wsum[1]) + (wsum[2] + wsum[3]);
}

// ---------------- Kernel 3: deterministic final reduce (applies ln2/P) ----------------
__global__ __launch_bounds__(256) void final_reduce(const float* __restrict__ partials,
                                                    float* __restrict__ out) {
    __shared__ float wsum[4];
    float acc = 0.0f;
    for (int t = threadIdx.x; t < NBLK; t += 256) acc += partials[t];
    for (int o = 32; o > 0; o >>= 1) acc += __shfl_down(acc, o, 64);
    if ((threadIdx.x & 63) == 0) wsum[threadIdx.x >> 6] = acc;
    __syncthreads();
    if (threadIdx.x == 0)
        out[0] = ((wsum[0] + wsum[1]) + (wsum[2] + wsum[3])) * (LN2 / PCOUNT);
}

extern "C" void kernel_launch(void* const* d_in, const int* in_sizes, int n_in,
                              void* d_out, int out_size, void* d_ws, size_t ws_size,
                              hipStream_t stream) {
    const float* x       = (const float*)d_in[0];   // (480,640) f32
    const float* gt      = (const float*)d_in[1];   // (P,) f32
    const int*   centers = (const int*)d_in[2];     // (5000,2) int32
    float* out = (float*)d_out;                     // scalar f32

    float* z        = (float*)d_ws;                 // NR floats (256B-aligned)
    float* partials = z + NR;                       // NBLK floats

    gather_z<<<(NR + 255) / 256, 256, 0, stream>>>(x, centers, z);
    pair_loss<<<NBLK, 256, 0, stream>>>(gt, z, partials);
    final_reduce<<<1, 256, 0, stream>>>(partials, out);
}

// Round 10
// 24.623 us; speedup vs baseline: 7.2770x; 1.1452x over previous
//
#include <hip/hip_runtime.h>
#include <stdint.h>

#define NR 5000
#define NRM1 4999
#define W 640
#define NBLK 2500          // block b: rows b and 4998-b == virtual space of 5000 elems
#define NELEM 20           // per-thread elements: 20*256 = 5120 >= 5000
#define PCOUNT 12497500.0f
#define LOG2E 1.44269504088896340736f
#define LN2   0.69314718055994530942f

// ---------------- Kernel 1: gather z = x[rows, cols] (once) ----------------
__global__ void gather_z(const float* __restrict__ x,
                         const int* __restrict__ centers,
                         float* __restrict__ z) {
    int t = blockIdx.x * blockDim.x + threadIdx.x;
    if (t < NR) {
        const int2 rc = ((const int2*)centers)[t];
        z[t] = x[rc.x * W + rc.y];
    }
}

// ---------------- Kernel 2: per-pair loss, batched-load version ----------------
// Virtual index v in [0,5000): v < len1 -> row1 (r=b), elem v: gt[off1+v], zj=z[b+1+v]
//                              v >= len1 -> row2 (r=4998-b), u=v-len1: gt[off2+u], zj=z[v]
// (row2: j = r2+1+u = v, a clean collapse.) All control is clamp+select; the 20
// gt loads are issued back-to-back before any use -> 20 outstanding VMEM/thread.
__global__ __launch_bounds__(256) void pair_loss(const float* __restrict__ gt,
                                                 const float* __restrict__ z,
                                                 float* __restrict__ partials) {
    __shared__ float sz[NR];        // 20000 B -> 8 blocks/CU
    __shared__ float wsum[4];
    const int tid = threadIdx.x;
    const int b = blockIdx.x;

    const float4* __restrict__ zf4 = (const float4*)z;
    for (int t = tid; t < NR / 4; t += 256)
        *(float4*)&sz[4 * t] = zf4[t];
    __syncthreads();

    const int r1 = b;
    const int r2 = NR - 2 - b;
    const int len1 = NRM1 - r1;                         // 4999-b
    const int off1 = r1 * NRM1 - (r1 * (r1 - 1)) / 2;   // fits i32
    const int off2 = r2 * NRM1 - (r2 * (r2 - 1)) / 2;
    const int off2v = off2 - len1;                      // virtual base for row2
    const int vmax = (r2 > r1) ? 5000 : len1;           // b==2499: single row
    const float zr1 = sz[r1];
    const float zr2 = sz[r2];

    // ---- batch-issue all NELEM gt loads (independent, fully unrolled) ----
    float g[NELEM];
    int vc[NELEM];
    #pragma unroll
    for (int k = 0; k < NELEM; ++k) {
        const int v = tid + 256 * k;
        const int c = min(v, vmax - 1);                 // clamp: keeps addr in-bounds
        vc[k] = c;
        const int ofs = (c < len1) ? off1 : off2v;
        g[k] = gt[ofs + c];
    }

    // ---- consume: z from LDS, loss in log2 domain, 4 accumulator chains ----
    float a0 = 0.0f, a1 = 0.0f, a2 = 0.0f, a3 = 0.0f;
    #pragma unroll
    for (int k = 0; k < NELEM; ++k) {
        const int c = vc[k];
        const bool row1 = c < len1;
        const float zj = sz[c + (row1 ? r1 + 1 : 0)];
        const float zr = row1 ? zr1 : zr2;
        const float gg = g[k];
        const float d  = zr - zj;
        const float dl = d * LOG2E;
        const float lg = __log2f(1.0f + exp2f(-gg * dl));
        float l = (gg != 0.0f) ? lg : d * dl;           // g==0 -> d^2/ln2
        l = (tid + 256 * k < vmax) ? l : 0.0f;          // mask padding elems
        if      ((k & 3) == 0) a0 += l;
        else if ((k & 3) == 1) a1 += l;
        else if ((k & 3) == 2) a2 += l;
        else                   a3 += l;
    }
    float acc = (a0 + a1) + (a2 + a3);

    // deterministic block reduction: wave shuffle tree + LDS across 4 waves
    for (int o = 32; o > 0; o >>= 1) acc += __shfl_down(acc, o, 64);
    if ((tid & 63) == 0) wsum[tid >> 6] = acc;
    __syncthreads();
    if (tid == 0)
        partials[b] = (wsum[0] + wsum[1]) + (wsum[2] + wsum[3]);
}

// ---------------- Kernel 3: deterministic final reduce (applies ln2/P) ----------------
__global__ __launch_bounds__(256) void final_reduce(const float* __restrict__ partials,
                                                    float* __restrict__ out) {
    __shared__ float wsum[4];
    float acc = 0.0f;
    const float4* __restrict__ p4 = (const float4*)partials;   // 2500 = 625 float4s
    for (int t = threadIdx.x; t < NBLK / 4; t += 256) {
        const float4 v = p4[t];
        acc += (v.x + v.y) + (v.z + v.w);
    }
    for (int o = 32; o > 0; o >>= 1) acc += __shfl_down(acc, o, 64);
    if ((threadIdx.x & 63) == 0) wsum[threadIdx.x >> 6] = acc;
    __syncthreads();
    if (threadIdx.x == 0)
        out[0] = ((wsum[0] + wsum[1]) + (wsum[2] + wsum[3])) * (LN2 / PCOUNT);
}

extern "C" void kernel_launch(void* const* d_in, const int* in_sizes, int n_in,
                              void* d_out, int out_size, void* d_ws, size_t ws_size,
                              hipStream_t stream) {
    const float* x       = (const float*)d_in[0];   // (480,640) f32
    const float* gt      = (const float*)d_in[1];   // (P,) f32
    const int*   centers = (const int*)d_in[2];     // (5000,2) int32
    float* out = (float*)d_out;                     // scalar f32

    float* z        = (float*)d_ws;                 // NR floats (16B-aligned)
    float* partials = z + NR;                       // NBLK floats

    gather_z<<<(NR + 255) / 256, 256, 0, stream>>>(x, centers, z);
    pair_loss<<<NBLK, 256, 0, stream>>>(gt, z, partials);
    final_reduce<<<1, 256, 0, stream>>>(partials, out);
}